// Round 5
// baseline (560.657 us; speedup 1.0000x reference)
//
#include <hip/hip_runtime.h>
#include <stdint.h>

#define N_PIX 131072
#define HW 16384
#define NSAMP 128
#define GSZ 129
#define ROWS_L 516
#define COLS_U 1032
#define INVALID_M 0xFFFFFFFFu

// ---------------- Threefry2x32 (exact JAX semantics, 20 rounds) ----------------
__host__ __device__ inline void tf2x32(uint32_t k0, uint32_t k1,
                                       uint32_t x0, uint32_t x1,
                                       uint32_t& o0, uint32_t& o1) {
  uint32_t ks2 = k0 ^ k1 ^ 0x1BD11BDAu;
  x0 += k0; x1 += k1;
#define TFR(r) { x0 += x1; x1 = (x1 << (r)) | (x1 >> (32 - (r))); x1 ^= x0; }
  TFR(13) TFR(15) TFR(26) TFR(6)   x0 += k1;  x1 += ks2 + 1u;
  TFR(17) TFR(29) TFR(16) TFR(24)  x0 += ks2; x1 += k0 + 2u;
  TFR(13) TFR(15) TFR(26) TFR(6)   x0 += k0;  x1 += k1 + 3u;
  TFR(17) TFR(29) TFR(16) TFR(24)  x0 += k1;  x1 += ks2 + 4u;
  TFR(13) TFR(15) TFR(26) TFR(6)   x0 += ks2; x1 += k0 + 5u;
#undef TFR
  o0 = x0; o1 = x1;
}

struct Keys4  { uint32_t a[4];  uint32_t b[4];  };
struct Keys12 { uint32_t a[12]; uint32_t b[12]; };

// Fence+counter "last block" gate (decoupled-lookback idiom; device-scope).
__device__ __forceinline__ bool last_block(unsigned* ctr, unsigned nblocks) {
  __shared__ unsigned rk_;
  __threadfence();
  __syncthreads();
  if (threadIdx.x == 0)
    rk_ = __hip_atomic_fetch_add(ctr, 1u, __ATOMIC_ACQ_REL, __HIP_MEMORY_SCOPE_AGENT);
  __syncthreads();
  if (rk_ != nblocks - 1u) return false;
  __threadfence();
  return true;
}

// ---------------- 1: mean(logits_u) in double ----------------
__global__ void k_sum(const float* __restrict__ x, double* out) {
  __shared__ double sm[256];
  int t = threadIdx.x;
  int base = blockIdx.x * 1024;
  double v = (double)x[base + t] + (double)x[base + 256 + t]
           + (double)x[base + 512 + t] + (double)x[base + 768 + t];
  sm[t] = v; __syncthreads();
  for (int o = 128; o > 0; o >>= 1) { if (t < o) sm[t] += sm[t + o]; __syncthreads(); }
  if (t == 0) atomicAdd(out, sm[0]);
}

// ---------------- 2: rank mantissa + hist1 + (last block) scan1 ----------------
__global__ void k_rank(const int* __restrict__ lab, const float* __restrict__ logu,
                       const double* __restrict__ sum, unsigned* __restrict__ m,
                       unsigned* __restrict__ cntu, unsigned* __restrict__ hist1,
                       int* __restrict__ half_, int* __restrict__ bin_,
                       int* __restrict__ base_, unsigned* __restrict__ ctr, Keys4 k2) {
  __shared__ unsigned cnt[4];
  int t = threadIdx.x;
  if (t < 4) cnt[t] = 0u;
  __syncthreads();
  int j = blockIdx.x * 256 + t;  // pair index 0..65535
  double thr = (*sum) / 131072.0;
  int i0 = j, i1 = j + 65536;
  unsigned m0 = INVALID_M, m1 = INVALID_M;
  uint32_t o0, o1;
  if ((double)logu[i0] >= thr) {
    int c = lab[i0];
    tf2x32(k2.a[c], k2.b[c], (uint32_t)j, (uint32_t)(j + 65536), o0, o1);
    m0 = o0 >> 9; atomicAdd(&cnt[c], 1u);
    atomicAdd(&hist1[c * 4096 + (m0 >> 11)], 1u);
  }
  if ((double)logu[i1] >= thr) {
    int c = lab[i1];
    tf2x32(k2.a[c], k2.b[c], (uint32_t)j, (uint32_t)(j + 65536), o0, o1);
    m1 = o1 >> 9; atomicAdd(&cnt[c], 1u);
    atomicAdd(&hist1[c * 4096 + (m1 >> 11)], 1u);
  }
  m[i0] = m0; m[i1] = m1;
  __syncthreads();
  if (t < 4 && cnt[t] > 0u) atomicAdd(&cntu[t], cnt[t]);

  if (!last_block(ctr, gridDim.x)) return;
  // scan1 for all 4 classes
  __shared__ unsigned part[256];
  for (int c = 0; c < 4; c++) {
    const unsigned* h = hist1 + c * 4096;
    unsigned s = 0;
    for (int k = 0; k < 16; k++) s += h[t * 16 + k];
    part[t] = s; __syncthreads();
    if (t == 0) {
      int half = (int)(cntu[c] / 2u); half_[c] = half;
      if (half <= 0) { bin_[c] = -1; base_[c] = 0; }
      else {
        unsigned target = (unsigned)(half - 1), cum = 0; int pb = 0;
        for (; pb < 256; pb++) { if (cum + part[pb] > target) break; cum += part[pb]; }
        int b = pb * 16;
        for (;; b++) { unsigned hb = h[b]; if (cum + hb > target) break; cum += hb; }
        bin_[c] = b; base_[c] = (int)cum;
      }
    }
    __syncthreads();
  }
}

// ---------------- 3: hist2 + (last block) scan2 ----------------
__global__ void k_h2s2(const int* __restrict__ lab, const unsigned* __restrict__ m,
                       const int* __restrict__ bin_, unsigned* __restrict__ hist2,
                       const int* __restrict__ half_, const int* __restrict__ base_,
                       unsigned* __restrict__ mstar_, int* __restrict__ t_,
                       unsigned* __restrict__ ctr) {
  int t = threadIdx.x;
  int i = blockIdx.x * 256 + t;
  unsigned mi = m[i];
  if (mi != INVALID_M) {
    int c = lab[i];
    if ((int)(mi >> 11) == bin_[c]) atomicAdd(&hist2[c * 2048 + (mi & 0x7FFu)], 1u);
  }
  if (!last_block(ctr, gridDim.x)) return;
  __shared__ unsigned part[256];
  for (int c = 0; c < 4; c++) {
    const unsigned* h = hist2 + c * 2048;
    unsigned s = 0;
    for (int k = 0; k < 8; k++) s += h[t * 8 + k];
    part[t] = s; __syncthreads();
    if (t == 0) {
      int half = half_[c];
      if (half <= 0) { mstar_[c] = 0u; t_[c] = 0; }
      else {
        unsigned target = (unsigned)(half - 1), cum = (unsigned)base_[c]; int pb = 0;
        for (; pb < 256; pb++) { if (cum + part[pb] > target) break; cum += part[pb]; }
        int v = pb * 8;
        for (;; v++) { unsigned hb = h[v]; if (cum + hb > target) break; cum += hb; }
        mstar_[c] = ((unsigned)bin_[c] << 11) | (unsigned)v;
        t_[c] = half - (int)cum;
      }
    }
    __syncthreads();
  }
}

// ---------------- 4: split + ties + (last block) tie-fix + scan + sample ----------------
__global__ void k_part(const int* __restrict__ pred, const int* __restrict__ lab,
                       const unsigned* __restrict__ m, const unsigned* __restrict__ mstar_,
                       const int* __restrict__ t_, int* __restrict__ tiecnt,
                       int* __restrict__ tielist,
                       uint8_t* __restrict__ lgid, uint8_t* __restrict__ ugid,
                       unsigned* __restrict__ bc, unsigned* __restrict__ totg,
                       int* __restrict__ sel, unsigned* __restrict__ ctr, Keys12 gk) {
  __shared__ unsigned cnt[12];
  int t = threadIdx.x;
  int lane = t & 63, w = t >> 6;
  int i = blockIdx.x * 256 + t;
  if (t < 12) cnt[t] = 0u;
  __syncthreads();
  int pc = pred[i];
  lgid[i] = (uint8_t)pc;
  atomicAdd(&cnt[pc], 1u);
  unsigned mi = m[i];
  int ug = 255;
  if (mi != INVALID_M) {
    int c = lab[i];
    unsigned ms = mstar_[c];
    if (mi < ms) ug = (c << 1);
    else if (mi > ms) ug = (c << 1) + 1;
    else {
      int p = atomicAdd(&tiecnt[c], 1);
      if (p < 128) tielist[c * 128 + p] = i;
      ug = 254;  // resolved by last block
    }
    if (ug < 8) atomicAdd(&cnt[4 + ug], 1u);
  }
  ugid[i] = (uint8_t)ug;
  __syncthreads();
  if (t < 12) bc[t * 512 + blockIdx.x] = cnt[t];

  if (!last_block(ctr, gridDim.x)) return;

  // ---- last block: tie-fix, scan, sample (all in LDS) ----
  __shared__ unsigned sbc[12][512];   // 24 KB
  __shared__ unsigned stot[12];
  __shared__ unsigned wtot[4];
  for (int k = t; k < 12 * 512; k += 256) ((unsigned*)sbc)[k] = bc[k];
  __syncthreads();
  // tie resolution (rank by counting — no sort needed)
  for (int c = 0; c < 4; c++) {
    int tc = tiecnt[c]; if (tc > 128) tc = 128;
    int tcv = t_[c];
    for (int a = t; a < tc; a += 256) {
      int i2 = tielist[c * 128 + a];
      int rk = 0;
      for (int b2 = 0; b2 < tc; b2++) rk += (tielist[c * 128 + b2] < i2);
      int ug2 = (c << 1) + ((rk < tcv) ? 0 : 1);
      ugid[i2] = (uint8_t)ug2;
      atomicAdd(&sbc[4 + ug2][i2 >> 8], 1u);
    }
  }
  __syncthreads();
  // exclusive scan of 512 per group (256 threads, 2 entries each)
  for (int g = 0; g < 12; g++) {
    unsigned v0 = sbc[g][2 * t], v1 = sbc[g][2 * t + 1];
    unsigned s2 = v0 + v1, x = s2;
    for (int o = 1; o < 64; o <<= 1) {
      unsigned y = __shfl_up(x, o, 64);
      if (lane >= o) x += y;
    }
    if (lane == 63) wtot[w] = x;
    __syncthreads();
    unsigned base = 0;
    for (int ww = 0; ww < 4; ww++) if (ww < w) base += wtot[ww];
    unsigned excl = base + x - s2;
    sbc[g][2 * t] = excl; sbc[g][2 * t + 1] = excl + v0;
    if (t == 255) stot[g] = excl + v0 + v1;
    __syncthreads();
  }
  if (t < 12) totg[t] = stot[t];
  __syncthreads();
  // sampling: 12 groups x 128 samples, 6 per thread
  for (int k = 0; k < 6; k++) {
    int idx = k * 256 + t;
    int g = idx >> 7, s = idx & 127;
    int nv = (int)stot[g];
    int res = 0;
    if (nv > 0) {
      uint32_t o0, o1; int jj = s & 63;
      tf2x32(gk.a[g], gk.b[g], (uint32_t)jj, (uint32_t)(jj + 64), o0, o1);
      uint32_t bits = (s < 64) ? o0 : o1;
      float u = __uint_as_float((bits >> 9) | 0x3f800000u) - 1.0f;
      int q = (nv >= NSAMP) ? (int)floorf(u * (float)nv) : (s % nv);
      if (q > nv - 1) q = nv - 1;
      int lo = 0, hi = 511;
      while (lo < hi) { int mid = (lo + hi + 1) >> 1; if (sbc[g][mid] <= (unsigned)q) lo = mid; else hi = mid - 1; }
      int rem = q - (int)sbc[g][lo];
      const uint8_t* arr = (g < 4) ? lgid : ugid;
      unsigned want = (g < 4) ? (unsigned)g : (unsigned)(g - 4);
      const unsigned* w32 = (const unsigned*)(arr + lo * 256);
      int found = -1;
      for (int ch = 0; ch < 4; ch++) {
        if (found >= 0) break;
        unsigned buf[16];
#pragma unroll
        for (int q2 = 0; q2 < 16; q2++) buf[q2] = w32[ch * 16 + q2];
        int mcnt = 0;
#pragma unroll
        for (int q2 = 0; q2 < 16; q2++) {
          unsigned bb = buf[q2];
          mcnt += (int)((bb & 255u) == want) + (int)(((bb >> 8) & 255u) == want)
                + (int)(((bb >> 16) & 255u) == want) + (int)(((bb >> 24) & 255u) == want);
        }
        if (rem >= mcnt) { rem -= mcnt; continue; }
#pragma unroll
        for (int q2 = 0; q2 < 16; q2++) {
          unsigned bb = buf[q2];
#pragma unroll
          for (int b3 = 0; b3 < 4; b3++) {
            if (found < 0 && ((bb >> (8 * b3)) & 255u) == want) {
              if (rem == 0) found = lo * 256 + ch * 64 + q2 * 4 + b3;
              else rem--;
            }
          }
        }
      }
      res = (found >= 0) ? found : 0;
    }
    sel[g * 128 + s] = res;
  }
}

// ---------------- 5: masked class-mean feature sums (half-rows, 6144 blocks) ----------------
__global__ void k_means(const float* __restrict__ fx, const float* __restrict__ fs,
                        const float* __restrict__ ffp,
                        const uint8_t* __restrict__ lgid, const uint8_t* __restrict__ ugid,
                        float* __restrict__ gsum) {
  int tensor = blockIdx.y;
  const float* f = (tensor == 0) ? fx : ((tensor == 1) ? fs : ffp);
  int rb = blockIdx.x >> 1;          // row unit: b*128+d
  int half = blockIdx.x & 1;
  int b = rb >> 7, d = rb & 127;
  int t = threadIdx.x;
  int lane = t & 63, w = t >> 6;
  const float4* row4 = (const float4*)(f + ((size_t)(b * 128 + d)) * HW) + half * 2048;
  const uchar4* gid4 = (const uchar4*)((tensor == 0 ? lgid : ugid) + (size_t)b * HW) + half * 2048;
  int par = tensor - 1;
  float a0 = 0.f, a1 = 0.f, a2 = 0.f, a3 = 0.f;
#pragma unroll
  for (int i = 0; i < 8; i++) {
    int idx = i * 256 + t;
    float4 v = row4[idx];
    uchar4 gg = gid4[idx];
    int s0, s1, s2, s3;
    if (tensor == 0) { s0 = gg.x; s1 = gg.y; s2 = gg.z; s3 = gg.w; }
    else {
      s0 = (gg.x < 8 && (gg.x & 1) == par) ? (gg.x >> 1) : -1;
      s1 = (gg.y < 8 && (gg.y & 1) == par) ? (gg.y >> 1) : -1;
      s2 = (gg.z < 8 && (gg.z & 1) == par) ? (gg.z >> 1) : -1;
      s3 = (gg.w < 8 && (gg.w & 1) == par) ? (gg.w >> 1) : -1;
    }
    a0 += ((s0 == 0) ? v.x : 0.f) + ((s1 == 0) ? v.y : 0.f) + ((s2 == 0) ? v.z : 0.f) + ((s3 == 0) ? v.w : 0.f);
    a1 += ((s0 == 1) ? v.x : 0.f) + ((s1 == 1) ? v.y : 0.f) + ((s2 == 1) ? v.z : 0.f) + ((s3 == 1) ? v.w : 0.f);
    a2 += ((s0 == 2) ? v.x : 0.f) + ((s1 == 2) ? v.y : 0.f) + ((s2 == 2) ? v.z : 0.f) + ((s3 == 2) ? v.w : 0.f);
    a3 += ((s0 == 3) ? v.x : 0.f) + ((s1 == 3) ? v.y : 0.f) + ((s2 == 3) ? v.z : 0.f) + ((s3 == 3) ? v.w : 0.f);
  }
  for (int o = 32; o > 0; o >>= 1) {
    a0 += __shfl_xor(a0, o, 64);
    a1 += __shfl_xor(a1, o, 64);
    a2 += __shfl_xor(a2, o, 64);
    a3 += __shfl_xor(a3, o, 64);
  }
  __shared__ float swsum[4][4];
  if (lane == 0) { swsum[w][0] = a0; swsum[w][1] = a1; swsum[w][2] = a2; swsum[w][3] = a3; }
  __syncthreads();
  if (t < 4) {
    float v = swsum[0][t] + swsum[1][t] + swsum[2][t] + swsum[3][t];
    int g = (tensor == 0) ? t : (4 + (t << 1) + par);
    atomicAdd(&gsum[g * 128 + d], v);
  }
}

// ---------------- 6: gather sampled/mean rows ----------------
__global__ void k_gather(const float* __restrict__ fx, const float* __restrict__ fs,
                         const float* __restrict__ ffp, const int* __restrict__ sel,
                         const float* __restrict__ gsum, const unsigned* __restrict__ tot,
                         float* __restrict__ featl, float* __restrict__ featuT) {
  int r = blockIdx.x, d = threadIdx.x;
  const float* src; int g, s;
  if (r < ROWS_L) { g = r / GSZ; s = r - g * GSZ; src = fx; }
  else {
    int col = r - ROWS_L; int gu = col / GSZ; s = col - gu * GSZ;
    g = 4 + gu; src = (gu & 1) ? ffp : fs;
  }
  float val;
  if (s == NSAMP) {
    int nv = (int)tot[g]; if (nv < 1) nv = 1;
    val = gsum[g * 128 + d] / (float)nv;
  } else {
    int p = sel[g * 128 + s];
    int b = p >> 14, hw = p & 16383;
    val = src[((size_t)(b * 128 + d)) * HW + hw];
  }
  if (r < ROWS_L) featl[r * 128 + d] = val;
  else featuT[d * COLS_U + (r - ROWS_L)] = val;
}

// ---------------- 7: per-anchor InfoNCE row + (last block) final scalar ----------------
__global__ void k_loss(const float* __restrict__ featl, const float* __restrict__ featuT,
                       const unsigned* __restrict__ tot, float* __restrict__ rowv,
                       unsigned* __restrict__ ctr, float* __restrict__ out) {
  int r = blockIdx.x, t = threadIdx.x;
  __shared__ float srow[128];
  __shared__ float slog[COLS_U];
  __shared__ float red[256];
  __shared__ double dred[256];
  __shared__ float sm_;
  __shared__ double sld;
  if (t < 128) srow[t] = featl[r * 128 + t];
  __syncthreads();
  for (int j = t; j < COLS_U; j += 256) {
    int gu = j / GSZ;
    float v;
    if (tot[4 + gu] > 0u) {
      float acc = 0.f;
      for (int d = 0; d < 128; d++) acc += srow[d] * featuT[d * COLS_U + j];
      v = acc / 0.1f;
    } else v = -1e9f;
    slog[j] = v;
  }
  __syncthreads();
  float mx = -3.4e38f;
  for (int j = t; j < COLS_U; j += 256) mx = fmaxf(mx, slog[j]);
  red[t] = mx; __syncthreads();
  for (int o = 128; o > 0; o >>= 1) { if (t < o) red[t] = fmaxf(red[t], red[t + o]); __syncthreads(); }
  if (t == 0) sm_ = red[0];
  __syncthreads();
  mx = sm_;
  double se = 0.0;
  for (int j = t; j < COLS_U; j += 256) se += (double)expf(slog[j] - mx);
  dred[t] = se; __syncthreads();
  for (int o = 128; o > 0; o >>= 1) { if (t < o) dred[t] += dred[t + o]; __syncthreads(); }
  if (t == 0) sld = log(dred[0]);
  __syncthreads();
  double logden = sld;
  int myc = r / GSZ;
  double ps = 0.0, pl = 0.0;
  for (int j = t; j < COLS_U; j += 256) {
    int gu = j / GSZ;
    if (tot[4 + gu] > 0u && (gu >> 1) == myc) {
      ps += 1.0; pl += (double)slog[j] - (double)mx - logden;
    }
  }
  dred[t] = ps; __syncthreads();
  for (int o = 128; o > 0; o >>= 1) { if (t < o) dred[t] += dred[t + o]; __syncthreads(); }
  double pst = dred[0]; __syncthreads();
  dred[t] = pl; __syncthreads();
  for (int o = 128; o > 0; o >>= 1) { if (t < o) dred[t] += dred[t + o]; __syncthreads(); }
  if (t == 0) rowv[r] = (float)(dred[0] / (pst + 1e-12));

  if (!last_block(ctr, gridDim.x)) return;
  // final scalar
  double s = 0.0, cn = 0.0;
  for (int r2 = t; r2 < ROWS_L; r2 += 256) {
    if (tot[r2 / GSZ] > 0u) { s += (double)rowv[r2]; cn += 1.0; }
  }
  dred[t] = s; red[t] = (float)cn; __syncthreads();
  for (int o = 128; o > 0; o >>= 1) {
    if (t < o) { dred[t] += dred[t + o]; red[t] += red[t + o]; }
    __syncthreads();
  }
  if (t == 0) {
    bool anyL = (tot[0] | tot[1] | tot[2] | tot[3]) > 0u;
    bool anyU = false;
    for (int g = 4; g < 12; g++) anyU = anyU || (tot[g] > 0u);
    double loss = -dred[0] / ((red[0] > 1.f) ? (double)red[0] : 1.0);
    out[0] = (anyL && anyU) ? (float)loss : 0.f;
  }
}

// ---------------- host ----------------
extern "C" void kernel_launch(void* const* d_in, const int* in_sizes, int n_in,
                              void* d_out, int out_size, void* d_ws, size_t ws_size,
                              hipStream_t stream) {
  const float* fx   = (const float*)d_in[0];
  const int*   pred = (const int*)d_in[1];
  const float* fs   = (const float*)d_in[3];
  const float* ffp  = (const float*)d_in[4];
  const float* logu = (const float*)d_in[5];
  const int*   lab  = (const int*)d_in[6];
  float* out = (float*)d_out;
  char* w = (char*)d_ws;

  // Host-side key derivation: key(42) -> 4x split(key,5), exact JAX threefry_split.
  uint32_t ka = 0u, kb = 42u;
  Keys4 K2; Keys12 GK;
  for (int c = 0; c < 4; c++) {
    uint32_t X0[5], X1[5];
    for (int j = 0; j < 5; j++) tf2x32(ka, kb, (uint32_t)j, (uint32_t)(j + 5), X0[j], X1[j]);
    uint32_t fl[10] = {X0[0],X0[1],X0[2],X0[3],X0[4],X1[0],X1[1],X1[2],X1[3],X1[4]};
    ka = fl[0]; kb = fl[1];
    GK.a[c] = fl[2];        GK.b[c] = fl[3];         // k1: labeled sampling
    K2.a[c] = fl[4];        K2.b[c] = fl[5];         // k2: rank uniforms
    GK.a[4 + 2*c] = fl[6];  GK.b[4 + 2*c] = fl[7];   // k3: fs sampling
    GK.a[5 + 2*c] = fl[8];  GK.b[5 + 2*c] = fl[9];   // k4: ffp sampling
  }

  double*   d_sum    = (double*)(w + 0);
  unsigned* d_cntu   = (unsigned*)(w + 64);
  int*      d_half   = (int*)(w + 128);
  int*      d_bin    = (int*)(w + 192);
  int*      d_base   = (int*)(w + 256);
  unsigned* d_mstar  = (unsigned*)(w + 320);
  int*      d_tt     = (int*)(w + 384);
  int*      d_tiecnt = (int*)(w + 448);
  unsigned* d_ctr    = (unsigned*)(w + 512);   // [0]=rank [1]=h2s2 [2]=part [3]=loss
  int*      d_tielist= (int*)(w + 1024);       // 4*128*4 = 2 KB
  unsigned* d_hist1  = (unsigned*)(w + 4096);  // 64 KB
  unsigned* d_hist2  = (unsigned*)(w + 69632); // 32 KB
  float*    d_gsum   = (float*)(w + 102400);   // 6 KB
  unsigned* d_tot    = (unsigned*)(w + 108544);
  unsigned* d_bc     = (unsigned*)(w + 108608); // 12*512*4 = 24 KB
  int*      d_sel    = (int*)(w + 133184);      // 6 KB
  unsigned* d_m      = (unsigned*)(w + 139328); // 512 KB
  uint8_t*  d_lgid   = (uint8_t*)(w + 663616);  // 128 KB
  uint8_t*  d_ugid   = (uint8_t*)(w + 794688);  // 128 KB
  float*    d_featl  = (float*)(w + 925760);    // 516*128*4
  float*    d_featuT = (float*)(w + 1189952);   // 128*1032*4
  float*    d_rowv   = (float*)(w + 1718336);   // 516*4

  // one memset covers sum..gsum (incl. counters, tie lists, hists)
  hipMemsetAsync(w, 0, 108544, stream);

  k_sum<<<128, 256, 0, stream>>>(logu, d_sum);
  k_rank<<<256, 256, 0, stream>>>(lab, logu, d_sum, d_m, d_cntu, d_hist1,
                                  d_half, d_bin, d_base, &d_ctr[0], K2);
  k_h2s2<<<512, 256, 0, stream>>>(lab, d_m, d_bin, d_hist2, d_half, d_base,
                                  d_mstar, d_tt, &d_ctr[1]);
  k_part<<<512, 256, 0, stream>>>(pred, lab, d_m, d_mstar, d_tt, d_tiecnt, d_tielist,
                                  d_lgid, d_ugid, d_bc, d_tot, d_sel, &d_ctr[2], GK);
  k_means<<<dim3(2048, 3), 256, 0, stream>>>(fx, fs, ffp, d_lgid, d_ugid, d_gsum);
  k_gather<<<ROWS_L + COLS_U, 128, 0, stream>>>(fx, fs, ffp, d_sel, d_gsum, d_tot,
                                                d_featl, d_featuT);
  k_loss<<<ROWS_L, 256, 0, stream>>>(d_featl, d_featuT, d_tot, d_rowv, &d_ctr[3], out);
  (void)in_sizes; (void)n_in; (void)out_size; (void)ws_size;
}

// Round 6
// 322.079 us; speedup vs baseline: 1.7407x; 1.7407x over previous
//
#include <hip/hip_runtime.h>
#include <stdint.h>

#define N_PIX 131072
#define HW 16384
#define NSAMP 128
#define GSZ 129
#define ROWS_L 516
#define COLS_U 1032
#define INVALID_M 0xFFFFFFFFu

// ---------------- Threefry2x32 (exact JAX semantics, 20 rounds) ----------------
__host__ __device__ inline void tf2x32(uint32_t k0, uint32_t k1,
                                       uint32_t x0, uint32_t x1,
                                       uint32_t& o0, uint32_t& o1) {
  uint32_t ks2 = k0 ^ k1 ^ 0x1BD11BDAu;
  x0 += k0; x1 += k1;
#define TFR(r) { x0 += x1; x1 = (x1 << (r)) | (x1 >> (32 - (r))); x1 ^= x0; }
  TFR(13) TFR(15) TFR(26) TFR(6)   x0 += k1;  x1 += ks2 + 1u;
  TFR(17) TFR(29) TFR(16) TFR(24)  x0 += ks2; x1 += k0 + 2u;
  TFR(13) TFR(15) TFR(26) TFR(6)   x0 += k0;  x1 += k1 + 3u;
  TFR(17) TFR(29) TFR(16) TFR(24)  x0 += k1;  x1 += ks2 + 4u;
  TFR(13) TFR(15) TFR(26) TFR(6)   x0 += ks2; x1 += k0 + 5u;
#undef TFR
  o0 = x0; o1 = x1;
}

struct Keys4  { uint32_t a[4];  uint32_t b[4];  };
struct Keys12 { uint32_t a[12]; uint32_t b[12]; };

// ---------------- 1: mean(logits_u) in double ----------------
__global__ void k_sum(const float* __restrict__ x, double* out) {
  __shared__ double sm[256];
  int t = threadIdx.x;
  int base = blockIdx.x * 1024;
  double v = (double)x[base + t] + (double)x[base + 256 + t]
           + (double)x[base + 512 + t] + (double)x[base + 768 + t];
  sm[t] = v; __syncthreads();
  for (int o = 128; o > 0; o >>= 1) { if (t < o) sm[t] += sm[t + o]; __syncthreads(); }
  if (t == 0) atomicAdd(out, sm[0]);
}

// ---------------- 2: per-pixel rank mantissa; LDS-staged class counters ----------------
__global__ void k_rankbits(const int* __restrict__ lab, const float* __restrict__ logu,
                           const double* __restrict__ sum, unsigned* __restrict__ m,
                           unsigned* __restrict__ cntu, Keys4 k2) {
  __shared__ unsigned cnt[4];
  int t = threadIdx.x;
  if (t < 4) cnt[t] = 0u;
  __syncthreads();
  int j = blockIdx.x * blockDim.x + t;  // 0..65535 (pair index)
  double thr = (*sum) / 131072.0;
  int i0 = j, i1 = j + 65536;
  unsigned m0 = INVALID_M, m1 = INVALID_M;
  uint32_t o0, o1;
  if ((double)logu[i0] >= thr) {
    int c = lab[i0];
    tf2x32(k2.a[c], k2.b[c], (uint32_t)j, (uint32_t)(j + 65536), o0, o1);
    m0 = o0 >> 9; atomicAdd(&cnt[c], 1u);
  }
  if ((double)logu[i1] >= thr) {
    int c = lab[i1];
    tf2x32(k2.a[c], k2.b[c], (uint32_t)j, (uint32_t)(j + 65536), o0, o1);
    m1 = o1 >> 9; atomicAdd(&cnt[c], 1u);
  }
  m[i0] = m0; m[i1] = m1;
  __syncthreads();
  if (t < 4 && cnt[t] > 0u) atomicAdd(&cntu[t], cnt[t]);
}

// ---------------- 3-6: radix select of `half` smallest (m, idx) per class ----------------
__global__ void k_hist1(const int* __restrict__ lab, const unsigned* __restrict__ m,
                        unsigned* __restrict__ hist1) {
  int i = blockIdx.x * 256 + threadIdx.x;
  unsigned mi = m[i];
  if (mi != INVALID_M) atomicAdd(&hist1[lab[i] * 4096 + (mi >> 11)], 1u);
}

__global__ void k_scan1(const unsigned* __restrict__ hist1, const unsigned* __restrict__ cntu,
                        int* __restrict__ half_, int* __restrict__ bin_, int* __restrict__ base_) {
  int c = blockIdx.x, t = threadIdx.x;
  __shared__ unsigned part[256];
  const unsigned* h = hist1 + c * 4096;
  unsigned s = 0;
  for (int k = 0; k < 16; k++) s += h[t * 16 + k];
  part[t] = s; __syncthreads();
  if (t == 0) {
    int half = (int)(cntu[c] / 2u); half_[c] = half;
    if (half <= 0) { bin_[c] = -1; base_[c] = 0; }
    else {
      unsigned target = (unsigned)(half - 1), cum = 0; int pb = 0;
      for (; pb < 256; pb++) { if (cum + part[pb] > target) break; cum += part[pb]; }
      int b = pb * 16;
      for (;; b++) { unsigned hb = h[b]; if (cum + hb > target) break; cum += hb; }
      bin_[c] = b; base_[c] = (int)cum;
    }
  }
}

__global__ void k_hist2(const int* __restrict__ lab, const unsigned* __restrict__ m,
                        const int* __restrict__ bin_, unsigned* __restrict__ hist2) {
  int i = blockIdx.x * 256 + threadIdx.x;
  unsigned mi = m[i];
  if (mi == INVALID_M) return;
  int c = lab[i];
  if ((int)(mi >> 11) == bin_[c]) atomicAdd(&hist2[c * 2048 + (mi & 0x7FFu)], 1u);
}

__global__ void k_scan2(const unsigned* __restrict__ hist2, const int* __restrict__ half_,
                        const int* __restrict__ base_, const int* __restrict__ bin_,
                        unsigned* __restrict__ mstar_, int* __restrict__ t_) {
  int c = blockIdx.x, t = threadIdx.x;
  __shared__ unsigned part[256];
  const unsigned* h = hist2 + c * 2048;
  unsigned s = 0;
  for (int k = 0; k < 8; k++) s += h[t * 8 + k];
  part[t] = s; __syncthreads();
  if (t == 0) {
    int half = half_[c];
    if (half <= 0) { mstar_[c] = 0u; t_[c] = 0; }
    else {
      unsigned target = (unsigned)(half - 1), cum = (unsigned)base_[c]; int pb = 0;
      for (; pb < 256; pb++) { if (cum + part[pb] > target) break; cum += part[pb]; }
      int v = pb * 8;
      for (;; v++) { unsigned hb = h[v]; if (cum + hb > target) break; cum += hb; }
      mstar_[c] = ((unsigned)bin_[c] << 11) | (unsigned)v;
      t_[c] = half - (int)cum;
    }
  }
}

__global__ void k_ties(const int* __restrict__ lab, const unsigned* __restrict__ m,
                       const unsigned* __restrict__ mstar_, int* __restrict__ tiecnt,
                       int* __restrict__ tielist) {
  int i = blockIdx.x * 256 + threadIdx.x;
  unsigned mi = m[i];
  if (mi == INVALID_M) return;
  int c = lab[i];
  if (mi == mstar_[c]) {
    int p = atomicAdd(&tiecnt[c], 1);
    if (p < 128) tielist[c * 128 + p] = i;
  }
}

// ---------------- 7: split masks + per-block group counts ----------------
// Tie ranking is count-based (order-independent) — no sort needed.
__global__ void k_split(const int* __restrict__ pred, const int* __restrict__ lab,
                        const unsigned* __restrict__ m, const unsigned* __restrict__ mstar_,
                        const int* __restrict__ t_, const int* __restrict__ tielist,
                        const int* __restrict__ tiecnt,
                        uint8_t* __restrict__ lgid, uint8_t* __restrict__ ugid,
                        unsigned* __restrict__ bc) {
  __shared__ unsigned cnt[12];
  int t = threadIdx.x;
  int i = blockIdx.x * 128 + t;
  if (t < 12) cnt[t] = 0u;
  __syncthreads();
  int pc = pred[i];
  lgid[i] = (uint8_t)pc;
  atomicAdd(&cnt[pc], 1u);
  unsigned mi = m[i];
  uint8_t ug = 255;
  if (mi != INVALID_M) {
    int c = lab[i];
    unsigned ms = mstar_[c];
    bool in_s;
    if (mi < ms) in_s = true;
    else if (mi > ms) in_s = false;
    else {
      int tc = tiecnt[c]; if (tc > 128) tc = 128;
      const int* L = tielist + c * 128;
      int rk = 0;
      for (int a = 0; a < tc; a++) if (L[a] < i) rk++;
      in_s = (rk < t_[c]);
    }
    ug = (uint8_t)((c << 1) + (in_s ? 0 : 1));
    atomicAdd(&cnt[4 + ug], 1u);
  }
  ugid[i] = ug;
  __syncthreads();
  if (t < 12) bc[t * 1024 + blockIdx.x] = cnt[t];
}

// ---------------- 8: exclusive scan of block counts per group (shfl-based) ----------------
__global__ void k_scanblocks(const unsigned* __restrict__ bc, unsigned* __restrict__ offs,
                             unsigned* __restrict__ tot) {
  __shared__ unsigned wsum[16];
  int t = threadIdx.x;
  int lane = t & 63, w = t >> 6;
  for (int g = 0; g < 12; g++) {
    unsigned v = bc[g * 1024 + t];
    unsigned x = v;
    for (int o = 1; o < 64; o <<= 1) {
      unsigned y = __shfl_up(x, o, 64);
      if (lane >= o) x += y;
    }
    if (lane == 63) wsum[w] = x;
    __syncthreads();
    if (w == 0 && lane < 16) {
      unsigned s = wsum[lane];
      for (int o = 1; o < 16; o <<= 1) {
        unsigned y = __shfl_up(s, o, 64);
        if (lane >= o) s += y;
      }
      wsum[lane] = s;
    }
    __syncthreads();
    unsigned base = (w > 0) ? wsum[w - 1] : 0u;
    offs[g * 1024 + t] = base + x - v;
    if (t == 1023) tot[g] = base + x;
    __syncthreads();
  }
}

// ---------------- 9: sample indices (replicates order[floor(u*nv)]) ----------------
__global__ void k_sample(Keys12 gk, const unsigned* __restrict__ offs,
                         const unsigned* __restrict__ tot,
                         const uint8_t* __restrict__ lgid, const uint8_t* __restrict__ ugid,
                         int* __restrict__ sel) {
  int g = blockIdx.x, s = threadIdx.x;  // 12 x 128
  int nv = (int)tot[g];
  if (nv <= 0) { sel[g * 128 + s] = 0; return; }
  uint32_t o0, o1; int jj = s & 63;
  tf2x32(gk.a[g], gk.b[g], (uint32_t)jj, (uint32_t)(jj + 64), o0, o1);
  uint32_t bits = (s < 64) ? o0 : o1;
  float u = __uint_as_float((bits >> 9) | 0x3f800000u) - 1.0f;
  int q = (nv >= NSAMP) ? (int)floorf(u * (float)nv) : (s % nv);
  if (q > nv - 1) q = nv - 1;
  const unsigned* of = offs + g * 1024;
  int lo = 0, hi = 1023;
  while (lo < hi) { int mid = (lo + hi + 1) >> 1; if (of[mid] <= (unsigned)q) lo = mid; else hi = mid - 1; }
  int rem = q - (int)of[lo];
  const uint8_t* arr = (g < 4) ? lgid : ugid;
  uint8_t want = (g < 4) ? (uint8_t)g : (uint8_t)(g - 4);
  const unsigned* w32 = (const unsigned*)(arr + lo * 128);
  unsigned buf[32];
#pragma unroll
  for (int k = 0; k < 32; k++) buf[k] = w32[k];
  int found = 0;
  for (int k = 0; k < 128; k++) {
    uint8_t bb = (uint8_t)(buf[k >> 2] >> ((k & 3) * 8));
    if (bb == want) { if (rem == 0) { found = lo * 128 + k; break; } rem--; }
  }
  sel[g * 128 + s] = found;
}

// ---------------- 10: masked class-mean feature sums (half-rows) ----------------
__global__ void k_means(const float* __restrict__ fx, const float* __restrict__ fs,
                        const float* __restrict__ ffp,
                        const uint8_t* __restrict__ lgid, const uint8_t* __restrict__ ugid,
                        float* __restrict__ gsum) {
  int tensor = blockIdx.y;
  const float* f = (tensor == 0) ? fx : ((tensor == 1) ? fs : ffp);
  int rb = blockIdx.x >> 1;          // row unit: b*128+d, 1024 rows
  int half = blockIdx.x & 1;
  int b = rb >> 7, d = rb & 127;
  int t = threadIdx.x;
  int lane = t & 63, w = t >> 6;
  const float4* row4 = (const float4*)(f + ((size_t)(b * 128 + d)) * HW) + half * 2048;
  const uchar4* gid4 = (const uchar4*)((tensor == 0 ? lgid : ugid) + (size_t)b * HW) + half * 2048;
  int par = tensor - 1;
  float a0 = 0.f, a1 = 0.f, a2 = 0.f, a3 = 0.f;
#pragma unroll
  for (int i = 0; i < 8; i++) {
    int idx = i * 256 + t;
    float4 v = row4[idx];
    uchar4 gg = gid4[idx];
    int s0, s1, s2, s3;
    if (tensor == 0) { s0 = gg.x; s1 = gg.y; s2 = gg.z; s3 = gg.w; }
    else {
      s0 = (gg.x != 255 && (gg.x & 1) == par) ? (gg.x >> 1) : -1;
      s1 = (gg.y != 255 && (gg.y & 1) == par) ? (gg.y >> 1) : -1;
      s2 = (gg.z != 255 && (gg.z & 1) == par) ? (gg.z >> 1) : -1;
      s3 = (gg.w != 255 && (gg.w & 1) == par) ? (gg.w >> 1) : -1;
    }
    a0 += ((s0 == 0) ? v.x : 0.f) + ((s1 == 0) ? v.y : 0.f) + ((s2 == 0) ? v.z : 0.f) + ((s3 == 0) ? v.w : 0.f);
    a1 += ((s0 == 1) ? v.x : 0.f) + ((s1 == 1) ? v.y : 0.f) + ((s2 == 1) ? v.z : 0.f) + ((s3 == 1) ? v.w : 0.f);
    a2 += ((s0 == 2) ? v.x : 0.f) + ((s1 == 2) ? v.y : 0.f) + ((s2 == 2) ? v.z : 0.f) + ((s3 == 2) ? v.w : 0.f);
    a3 += ((s0 == 3) ? v.x : 0.f) + ((s1 == 3) ? v.y : 0.f) + ((s2 == 3) ? v.z : 0.f) + ((s3 == 3) ? v.w : 0.f);
  }
  for (int o = 32; o > 0; o >>= 1) {
    a0 += __shfl_xor(a0, o, 64);
    a1 += __shfl_xor(a1, o, 64);
    a2 += __shfl_xor(a2, o, 64);
    a3 += __shfl_xor(a3, o, 64);
  }
  __shared__ float swsum[4][4];
  if (lane == 0) { swsum[w][0] = a0; swsum[w][1] = a1; swsum[w][2] = a2; swsum[w][3] = a3; }
  __syncthreads();
  if (t < 4) {
    float v = swsum[0][t] + swsum[1][t] + swsum[2][t] + swsum[3][t];
    int g = (tensor == 0) ? t : (4 + (t << 1) + par);
    atomicAdd(&gsum[g * 128 + d], v);
  }
}

// ---------------- 11: gather sampled/mean rows ----------------
__global__ void k_gather(const float* __restrict__ fx, const float* __restrict__ fs,
                         const float* __restrict__ ffp, const int* __restrict__ sel,
                         const float* __restrict__ gsum, const unsigned* __restrict__ tot,
                         float* __restrict__ featl, float* __restrict__ featuT) {
  int r = blockIdx.x, d = threadIdx.x;
  const float* src; int g, s;
  if (r < ROWS_L) { g = r / GSZ; s = r - g * GSZ; src = fx; }
  else {
    int col = r - ROWS_L; int gu = col / GSZ; s = col - gu * GSZ;
    g = 4 + gu; src = (gu & 1) ? ffp : fs;
  }
  float val;
  if (s == NSAMP) {
    int nv = (int)tot[g]; if (nv < 1) nv = 1;
    val = gsum[g * 128 + d] / (float)nv;
  } else {
    int p = sel[g * 128 + s];
    int b = p >> 14, hw = p & 16383;
    val = src[((size_t)(b * 128 + d)) * HW + hw];
  }
  if (r < ROWS_L) featl[r * 128 + d] = val;
  else featuT[d * COLS_U + (r - ROWS_L)] = val;
}

// ---------------- 12: per-anchor InfoNCE row ----------------
__global__ void k_loss(const float* __restrict__ featl, const float* __restrict__ featuT,
                       const unsigned* __restrict__ tot, float* __restrict__ rowv) {
  int r = blockIdx.x, t = threadIdx.x;
  __shared__ float srow[128];
  __shared__ float slog[COLS_U];
  __shared__ float red[256];
  __shared__ float sbc[2];
  if (t < 128) srow[t] = featl[r * 128 + t];
  __syncthreads();
  for (int j = t; j < COLS_U; j += 256) {
    int gu = j / GSZ;
    float v;
    if (tot[4 + gu] > 0u) {
      float acc = 0.f;
      for (int d = 0; d < 128; d++) acc += srow[d] * featuT[d * COLS_U + j];
      v = acc / 0.1f;
    } else v = -1e9f;
    slog[j] = v;
  }
  __syncthreads();
  float mx = -3.4e38f;
  for (int j = t; j < COLS_U; j += 256) mx = fmaxf(mx, slog[j]);
  red[t] = mx; __syncthreads();
  for (int o = 128; o > 0; o >>= 1) { if (t < o) red[t] = fmaxf(red[t], red[t + o]); __syncthreads(); }
  if (t == 0) sbc[0] = red[0];
  __syncthreads();
  mx = sbc[0];
  float se = 0.f;
  for (int j = t; j < COLS_U; j += 256) se += expf(slog[j] - mx);
  red[t] = se; __syncthreads();
  for (int o = 128; o > 0; o >>= 1) { if (t < o) red[t] += red[t + o]; __syncthreads(); }
  if (t == 0) sbc[1] = logf(red[0]);
  __syncthreads();
  float logden = sbc[1];
  int myc = r / GSZ;
  float ps = 0.f, pl = 0.f;
  for (int j = t; j < COLS_U; j += 256) {
    int gu = j / GSZ;
    if (tot[4 + gu] > 0u && (gu >> 1) == myc) { ps += 1.f; pl += slog[j] - mx - logden; }
  }
  red[t] = ps; __syncthreads();
  for (int o = 128; o > 0; o >>= 1) { if (t < o) red[t] += red[t + o]; __syncthreads(); }
  float pst = red[0]; __syncthreads();
  red[t] = pl; __syncthreads();
  for (int o = 128; o > 0; o >>= 1) { if (t < o) red[t] += red[t + o]; __syncthreads(); }
  if (t == 0) rowv[r] = red[0] / (pst + 1e-12f);
}

// ---------------- 13: final reduction to scalar ----------------
__global__ void k_final(const float* __restrict__ rowv, const unsigned* __restrict__ tot,
                        float* __restrict__ out) {
  __shared__ float red[256];
  __shared__ float redc[256];
  int t = threadIdx.x;
  float s = 0.f, cn = 0.f;
  for (int r = t; r < ROWS_L; r += 256) {
    if (tot[r / GSZ] > 0u) { s += rowv[r]; cn += 1.f; }
  }
  red[t] = s; redc[t] = cn; __syncthreads();
  for (int o = 128; o > 0; o >>= 1) {
    if (t < o) { red[t] += red[t + o]; redc[t] += redc[t + o]; }
    __syncthreads();
  }
  if (t == 0) {
    bool anyL = (tot[0] | tot[1] | tot[2] | tot[3]) > 0u;
    bool anyU = false;
    for (int g = 4; g < 12; g++) anyU = anyU || (tot[g] > 0u);
    float loss = -red[0] / fmaxf(redc[0], 1.f);
    out[0] = (anyL && anyU) ? loss : 0.f;
  }
}

// ---------------- host ----------------
extern "C" void kernel_launch(void* const* d_in, const int* in_sizes, int n_in,
                              void* d_out, int out_size, void* d_ws, size_t ws_size,
                              hipStream_t stream) {
  const float* fx   = (const float*)d_in[0];
  const int*   pred = (const int*)d_in[1];
  const float* fs   = (const float*)d_in[3];
  const float* ffp  = (const float*)d_in[4];
  const float* logu = (const float*)d_in[5];
  const int*   lab  = (const int*)d_in[6];
  float* out = (float*)d_out;
  char* w = (char*)d_ws;

  // Host-side key derivation: key(42) -> 4x split(key,5), exact JAX threefry_split.
  uint32_t ka = 0u, kb = 42u;
  Keys4 K2; Keys12 GK;
  for (int c = 0; c < 4; c++) {
    uint32_t X0[5], X1[5];
    for (int j = 0; j < 5; j++) tf2x32(ka, kb, (uint32_t)j, (uint32_t)(j + 5), X0[j], X1[j]);
    uint32_t fl[10] = {X0[0],X0[1],X0[2],X0[3],X0[4],X1[0],X1[1],X1[2],X1[3],X1[4]};
    ka = fl[0]; kb = fl[1];
    GK.a[c] = fl[2];        GK.b[c] = fl[3];         // k1: labeled sampling
    K2.a[c] = fl[4];        K2.b[c] = fl[5];         // k2: rank uniforms
    GK.a[4 + 2*c] = fl[6];  GK.b[4 + 2*c] = fl[7];   // k3: fs sampling
    GK.a[5 + 2*c] = fl[8];  GK.b[5 + 2*c] = fl[9];   // k4: ffp sampling
  }

  // Workspace layout: everything needing zero-init lives in [0, 107520).
  double*   d_sum    = (double*)(w + 0);
  unsigned* d_cntu   = (unsigned*)(w + 64);
  int*      d_half   = (int*)(w + 128);
  int*      d_bin    = (int*)(w + 192);
  int*      d_base   = (int*)(w + 256);
  unsigned* d_mstar  = (unsigned*)(w + 320);
  int*      d_tt     = (int*)(w + 384);
  int*      d_tiecnt = (int*)(w + 448);
  int*      d_tielist= (int*)(w + 512);        // 2 KB
  unsigned* d_hist1  = (unsigned*)(w + 4096);  // 64 KB
  unsigned* d_hist2  = (unsigned*)(w + 69632); // 32 KB
  float*    d_gsum   = (float*)(w + 101376);   // 6 KB -> ends 107520
  unsigned* d_tot    = (unsigned*)(w + 107520);
  unsigned* d_bc     = (unsigned*)(w + 107584); // 48 KB
  unsigned* d_offs   = (unsigned*)(w + 156736); // 48 KB
  int*      d_sel    = (int*)(w + 205888);      // 6 KB
  unsigned* d_m      = (unsigned*)(w + 212032); // 512 KB
  uint8_t*  d_lgid   = (uint8_t*)(w + 736320);  // 128 KB
  uint8_t*  d_ugid   = (uint8_t*)(w + 867392);  // 128 KB
  float*    d_featl  = (float*)(w + 998464);    // 258 KB
  float*    d_featuT = (float*)(w + 1262656);   // 516 KB
  float*    d_rowv   = (float*)(w + 1791040);   // 2 KB

  hipMemsetAsync(w, 0, 107520, stream);  // sum, counters, ties, hists, gsum

  k_sum<<<128, 256, 0, stream>>>(logu, d_sum);
  k_rankbits<<<256, 256, 0, stream>>>(lab, logu, d_sum, d_m, d_cntu, K2);
  k_hist1<<<512, 256, 0, stream>>>(lab, d_m, d_hist1);
  k_scan1<<<4, 256, 0, stream>>>(d_hist1, d_cntu, d_half, d_bin, d_base);
  k_hist2<<<512, 256, 0, stream>>>(lab, d_m, d_bin, d_hist2);
  k_scan2<<<4, 256, 0, stream>>>(d_hist2, d_half, d_base, d_bin, d_mstar, d_tt);
  k_ties<<<512, 256, 0, stream>>>(lab, d_m, d_mstar, d_tiecnt, d_tielist);
  k_split<<<1024, 128, 0, stream>>>(pred, lab, d_m, d_mstar, d_tt, d_tielist, d_tiecnt,
                                    d_lgid, d_ugid, d_bc);
  k_scanblocks<<<1, 1024, 0, stream>>>(d_bc, d_offs, d_tot);
  k_sample<<<12, 128, 0, stream>>>(GK, d_offs, d_tot, d_lgid, d_ugid, d_sel);
  k_means<<<dim3(2048, 3), 256, 0, stream>>>(fx, fs, ffp, d_lgid, d_ugid, d_gsum);
  k_gather<<<ROWS_L + COLS_U, 128, 0, stream>>>(fx, fs, ffp, d_sel, d_gsum, d_tot,
                                                d_featl, d_featuT);
  k_loss<<<ROWS_L, 256, 0, stream>>>(d_featl, d_featuT, d_tot, d_rowv);
  k_final<<<1, 256, 0, stream>>>(d_rowv, d_tot, out);
  (void)in_sizes; (void)n_in; (void)out_size; (void)ws_size;
}